// Round 1
// baseline (141.799 us; speedup 1.0000x reference)
//
#include <hip/hip_runtime.h>
#include <hip/hip_bf16.h>
#include <cstdint>

// CapsuleLinear: B=64, I=512, O=64, LIN=8, LOUT=16, 3 routing iterations.
// x: [64,512,8] f32, W: [64,512,16,8] f32, bias: [64,16] f32, out: [64,64,16] f32.
//
// ws layout: priors bf16 [b][i][o][v] (67,108,864 B), then 4 out buffers
// [64][64][16] f32 (4 x 262,144 B). Total ws needed: 68,157,440 B.

typedef float float4v __attribute__((ext_vector_type(4)));
typedef unsigned short ushort8 __attribute__((ext_vector_type(8)));

__device__ __forceinline__ float bf2f(unsigned short u) {
    union { unsigned int ui; float f; } cv;
    cv.ui = ((unsigned int)u) << 16;
    return cv.f;
}
__device__ __forceinline__ unsigned short f2bf(float f) {
    union { float f; unsigned int ui; } cv;
    cv.f = f;
    unsigned int u = cv.ui;
    unsigned int r = u + 0x7FFFu + ((u >> 16) & 1u);  // RNE
    return (unsigned short)(r >> 16);
}

// ---------------------------------------------------------------------------
// K1: priors[b,i,o,v] = sum_l W[o,i,v,l] * x[b,i,l], stored bf16.
// One block per i (512 blocks). W[:,i,:,:] staged in 16-o chunks to LDS,
// each thread owns one o-row (128 W floats in regs) and 4 b's per chunk.
// ---------------------------------------------------------------------------
__global__ __launch_bounds__(256) void k_priors(const float* __restrict__ W,
                                                const float* __restrict__ x,
                                                unsigned short* __restrict__ priors) {
    const int i = blockIdx.x;      // 0..511
    const int t = threadIdx.x;
    __shared__ float Wl[16 * 132]; // [o_local][v*8+l], row stride 132 (pad: 2-way max)
    __shared__ float xl[512];      // [b][l]

    if (t < 128) {
        float4v v = *(const float4v*)(x + ((size_t)(t >> 1) * 512 + i) * 8 + (size_t)(t & 1) * 4);
        *(float4v*)(xl + t * 4) = v;
    }

    const int r  = t & 15;   // o within chunk
    const int bq = t >> 4;   // 0..15

    for (int oc = 0; oc < 4; ++oc) {
        __syncthreads();  // protects Wl reuse (and xl on first pass)
        // stage 16 o-rows (2048 floats) of W for this i
        #pragma unroll
        for (int k = 0; k < 2; ++k) {
            int j  = t + k * 256;   // 0..511 float4s
            int ol = j >> 5;        // 0..15
            int r4 = j & 31;
            float4v v = *(const float4v*)(W + ((size_t)((oc * 16 + ol) * 512 + i)) * 128 + (size_t)r4 * 4);
            *(float4v*)(Wl + ol * 132 + r4 * 4) = v;
        }
        __syncthreads();

        // this thread's full o-row into registers
        float4v wreg[32];
        const float4v* wp = (const float4v*)(Wl + r * 132);
        #pragma unroll
        for (int j = 0; j < 32; ++j) wreg[j] = wp[j];

        const int o = oc * 16 + r;
        #pragma unroll
        for (int k = 0; k < 4; ++k) {
            const int b = bq + 16 * k;
            float4v xr0 = ((const float4v*)(xl + b * 8))[0];
            float4v xr1 = ((const float4v*)(xl + b * 8))[1];
            ushort8 u0, u1;
            #pragma unroll
            for (int v = 0; v < 16; ++v) {
                float s = 0.0f;
                #pragma unroll
                for (int l = 0; l < 8; ++l) {
                    int idx = v * 8 + l;
                    float wv = wreg[idx >> 2][idx & 3];
                    float xv = (l < 4) ? xr0[l & 3] : xr1[l & 3];
                    s = fmaf(wv, xv, s);
                }
                unsigned short hb = f2bf(s);
                if (v < 8) u0[v] = hb; else u1[v - 8] = hb;
            }
            unsigned short* dst = priors + ((size_t)(b * 512 + i) * 64 + o) * 16;
            *(ushort8*)(dst) = u0;
            *(ushort8*)(dst + 8) = u1;
        }
    }
}

// ---------------------------------------------------------------------------
// K1b: out0[b,o,v] = sum_{i,l} W[o,i,v,l] * x[b,i,l]  (direct GEMM, fp32).
// Unnormalized sum == mean up to scale; only consumed through normalize().
// Also zeros out1..out3 (atomicAdd targets of the routing kernels).
// Grid 512 = (o:64) x (bh:8); thread = (v:16, bs:8, ih:2).
// ---------------------------------------------------------------------------
__global__ __launch_bounds__(256) void k_out0(const float* __restrict__ W,
                                              const float* __restrict__ x,
                                              float* __restrict__ outb) {
    const int o  = blockIdx.x >> 3;
    const int bh = blockIdx.x & 7;
    const int t  = threadIdx.x;

    // zero out1..out3 (196608 floats across 131072 threads)
    {
        float* z = outb + 65536;
        for (int j = blockIdx.x * 256 + t; j < 3 * 65536; j += 512 * 256) z[j] = 0.0f;
    }

    const int v  = t & 15;
    const int bs = (t >> 4) & 7;
    const int ih = t >> 7;
    const int b  = bh * 8 + bs;

    const float* wbase = W + (size_t)o * 65536 + (size_t)v * 8;
    const float* xbase = x + (size_t)b * 4096;

    float acc = 0.0f;
    for (int ii = 0; ii < 256; ++ii) {
        const int i = ih * 256 + ii;
        float4v w0 = *(const float4v*)(wbase + (size_t)i * 128);
        float4v w1 = *(const float4v*)(wbase + (size_t)i * 128 + 4);
        float4v x0 = *(const float4v*)(xbase + i * 8);
        float4v x1 = *(const float4v*)(xbase + i * 8 + 4);
        acc += w0[0]*x0[0] + w0[1]*x0[1] + w0[2]*x0[2] + w0[3]*x0[3]
             + w1[0]*x1[0] + w1[1]*x1[1] + w1[2]*x1[2] + w1[3]*x1[3];
    }

    __shared__ float red[128];
    if (ih == 1) red[t - 128] = acc;
    __syncthreads();
    if (ih == 0) {
        outb[(size_t)b * 1024 + o * 16 + v] = acc + red[t];
    }
}

// ---------------------------------------------------------------------------
// K_route: one fused routing iteration.
//   logits[b,o,i] = dot(priors[b,i,o,:], normalize(out_prev[b,o,:]))
//   probs = softmax over o; out_next[b,o,v] += sum_i probs * priors
// Grid 512 = (b:64) x (h:8), each block owns i in [h*64, h*64+64).
// lane == o (wave of 64 == O), softmax is a wave shuffle-reduce.
// ---------------------------------------------------------------------------
__global__ __launch_bounds__(256) void k_route(const unsigned short* __restrict__ priors,
                                               const float* __restrict__ out_prev,
                                               float* __restrict__ out_next) {
    const int b    = blockIdx.x >> 3;
    const int h    = blockIdx.x & 7;
    const int t    = threadIdx.x;
    const int w    = t >> 6;
    const int lane = t & 63;

    __shared__ float noutT[16 * 64];   // [v][o]
    __shared__ float accbuf[4 * 1088]; // [wave][o*17+v] (pad 17: conflict-free)

    if (t < 64) {
        const float* po = out_prev + (size_t)b * 1024 + t * 16;
        float vv[16]; float n2 = 0.0f;
        #pragma unroll
        for (int j = 0; j < 16; ++j) { vv[j] = po[j]; n2 += vv[j] * vv[j]; }
        float n = fmaxf(sqrtf(n2), 1e-12f);
        float inv = 1.0f / n;
        #pragma unroll
        for (int j = 0; j < 16; ++j) noutT[j * 64 + t] = vv[j] * inv;
    }
    __syncthreads();

    float nr[16];
    #pragma unroll
    for (int j = 0; j < 16; ++j) nr[j] = noutT[j * 64 + lane];

    float acc[16];
    #pragma unroll
    for (int j = 0; j < 16; ++j) acc[j] = 0.0f;

    const size_t base = (size_t)b * 524288 + (size_t)lane * 16;
    for (int k = 0; k < 16; ++k) {
        const int i = h * 64 + w + 4 * k;
        const ushort8* pp = (const ushort8*)(priors + base + (size_t)i * 1024);
        ushort8 u0 = pp[0], u1 = pp[1];
        float pf[16];
        #pragma unroll
        for (int j = 0; j < 8; ++j) { pf[j] = bf2f(u0[j]); pf[8 + j] = bf2f(u1[j]); }

        float logit = 0.0f;
        #pragma unroll
        for (int j = 0; j < 16; ++j) logit = fmaf(pf[j], nr[j], logit);

        float m = logit;
        #pragma unroll
        for (int d = 1; d < 64; d <<= 1) m = fmaxf(m, __shfl_xor(m, d));
        float e = __expf(logit - m);
        float s = e;
        #pragma unroll
        for (int d = 1; d < 64; d <<= 1) s += __shfl_xor(s, d);
        float p = e / s;

        #pragma unroll
        for (int j = 0; j < 16; ++j) acc[j] = fmaf(p, pf[j], acc[j]);
    }

    #pragma unroll
    for (int j = 0; j < 16; ++j) accbuf[w * 1088 + lane * 17 + j] = acc[j];
    __syncthreads();

    for (int j = t; j < 1024; j += 256) {
        const int o = j >> 4, v = j & 15;
        const int idx = o * 17 + v;
        float s = accbuf[idx] + accbuf[1088 + idx] + accbuf[2176 + idx] + accbuf[3264 + idx];
        atomicAdd(out_next + (size_t)b * 1024 + j, s);
    }
}

// ---------------------------------------------------------------------------
// K_fin: out = squash(out3) + bias;  squash(x) = x * (||x|| / (1 + ||x||^2))
// ---------------------------------------------------------------------------
__global__ __launch_bounds__(64) void k_fin(const float* __restrict__ outl,
                                            const float* __restrict__ bias,
                                            float* __restrict__ out) {
    const int b = blockIdx.x;
    const int o = threadIdx.x;
    const float* p = outl + (size_t)b * 1024 + o * 16;
    float vv[16]; float n2 = 0.0f;
    #pragma unroll
    for (int j = 0; j < 16; ++j) { vv[j] = p[j]; n2 += vv[j] * vv[j]; }
    float n = sqrtf(n2);
    float scale = n / (1.0f + n2);
    float* q = out + (size_t)b * 1024 + o * 16;
    #pragma unroll
    for (int j = 0; j < 16; ++j) q[j] = vv[j] * scale + bias[o * 16 + j];
}

extern "C" void kernel_launch(void* const* d_in, const int* in_sizes, int n_in,
                              void* d_out, int out_size, void* d_ws, size_t ws_size,
                              hipStream_t stream) {
    const float* x    = (const float*)d_in[0];   // [64,512,8]
    const float* W    = (const float*)d_in[1];   // [64,512,16,8]
    const float* bias = (const float*)d_in[2];   // [64,16]
    float* out = (float*)d_out;                  // [64,64,16]

    unsigned short* priors = (unsigned short*)d_ws;                      // 67,108,864 B
    float* outb = (float*)((char*)d_ws + (size_t)64 * 512 * 64 * 16 * 2); // 4 x 65536 f32

    k_priors<<<512, 256, 0, stream>>>(W, x, priors);
    k_out0  <<<512, 256, 0, stream>>>(W, x, outb);
    k_route <<<512, 256, 0, stream>>>(priors, outb,               outb + 65536);
    k_route <<<512, 256, 0, stream>>>(priors, outb + 65536,       outb + 2 * 65536);
    k_route <<<512, 256, 0, stream>>>(priors, outb + 2 * 65536,   outb + 3 * 65536);
    k_fin   <<<64, 64, 0, stream>>>(outb + 3 * 65536, bias, out);
}

// Round 2
// 99.741 us; speedup vs baseline: 1.4217x; 1.4217x over previous
//
#include <hip/hip_runtime.h>
#include <hip/hip_bf16.h>
#include <cstdint>

// CapsuleLinear: B=64, I=512, O=64, LIN=8, LOUT=16, 3 routing iterations.
// x: [64,512,8] f32, W: [64,512,16,8] f32, bias: [64,16] f32, out: [64,64,16] f32.
//
// ws layout: priors bf16 [b][i][o][v] (67,108,864 B), then 4 out buffers
// [64][64][16] f32 (4 x 262,144 B). Total ws needed: 68,157,440 B.

typedef float float4v __attribute__((ext_vector_type(4)));
typedef float float2v __attribute__((ext_vector_type(2)));
typedef unsigned short ushort8 __attribute__((ext_vector_type(8)));

__device__ __forceinline__ float bf2f(unsigned short u) {
    union { unsigned int ui; float f; } cv;
    cv.ui = ((unsigned int)u) << 16;
    return cv.f;
}
__device__ __forceinline__ unsigned short f2bf(float f) {
    union { float f; unsigned int ui; } cv;
    cv.f = f;
    unsigned int u = cv.ui;
    unsigned int r = u + 0x7FFFu + ((u >> 16) & 1u);  // RNE
    return (unsigned short)(r >> 16);
}

// ---------------------------------------------------------------------------
// K1: priors[b,i,o,v] = sum_l W[o,i,v,l] * x[b,i,l], stored bf16.
// One block per i (512 blocks). W[:,i,:,:] staged in 16-o chunks to LDS,
// each thread owns one o-row (128 W floats in regs) and 4 b's per chunk.
// Also zeros the 4 out buffers (out0 is k_sum0's atomic target).
// ---------------------------------------------------------------------------
__global__ __launch_bounds__(256) void k_priors(const float* __restrict__ W,
                                                const float* __restrict__ x,
                                                unsigned short* __restrict__ priors,
                                                float* __restrict__ outb) {
    const int i = blockIdx.x;      // 0..511
    const int t = threadIdx.x;
    __shared__ float Wl[16 * 132]; // [o_local][v*8+l], row stride 132 (pad: 2-way max)
    __shared__ float xl[512];      // [b][l]

    // zero out0..out3 (262144 floats over 512x256 threads = 2 each)
    {
        int j = (blockIdx.x * 256 + t) * 2;
        *(float2v*)(outb + j) = (float2v){0.0f, 0.0f};
    }

    if (t < 128) {
        float4v v = *(const float4v*)(x + ((size_t)(t >> 1) * 512 + i) * 8 + (size_t)(t & 1) * 4);
        *(float4v*)(xl + t * 4) = v;
    }

    const int r  = t & 15;   // o within chunk
    const int bq = t >> 4;   // 0..15

    for (int oc = 0; oc < 4; ++oc) {
        __syncthreads();  // protects Wl reuse (and xl on first pass)
        // stage 16 o-rows (2048 floats) of W for this i
        #pragma unroll
        for (int k = 0; k < 2; ++k) {
            int j  = t + k * 256;   // 0..511 float4s
            int ol = j >> 5;        // 0..15
            int r4 = j & 31;
            float4v v = *(const float4v*)(W + ((size_t)((oc * 16 + ol) * 512 + i)) * 128 + (size_t)r4 * 4);
            *(float4v*)(Wl + ol * 132 + r4 * 4) = v;
        }
        __syncthreads();

        // this thread's full o-row into registers
        float4v wreg[32];
        const float4v* wp = (const float4v*)(Wl + r * 132);
        #pragma unroll
        for (int j = 0; j < 32; ++j) wreg[j] = wp[j];

        const int o = oc * 16 + r;
        #pragma unroll
        for (int k = 0; k < 4; ++k) {
            const int b = bq + 16 * k;
            float4v xr0 = ((const float4v*)(xl + b * 8))[0];
            float4v xr1 = ((const float4v*)(xl + b * 8))[1];
            ushort8 u0, u1;
            #pragma unroll
            for (int v = 0; v < 16; ++v) {
                float s = 0.0f;
                #pragma unroll
                for (int l = 0; l < 8; ++l) {
                    int idx = v * 8 + l;
                    float wv = wreg[idx >> 2][idx & 3];
                    float xv = (l < 4) ? xr0[l & 3] : xr1[l & 3];
                    s = fmaf(wv, xv, s);
                }
                unsigned short hb = f2bf(s);
                if (v < 8) u0[v] = hb; else u1[v - 8] = hb;
            }
            unsigned short* dst = priors + ((size_t)(b * 512 + i) * 64 + o) * 16;
            *(ushort8*)(dst) = u0;
            *(ushort8*)(dst + 8) = u1;
        }
    }
}

// ---------------------------------------------------------------------------
// K_sum0: out0[b,o,v] = sum_i priors[b,i,o,v]  (bf16 read, fp32 accumulate).
// Replaces the W-re-reading GEMM: streams priors once, fully coalesced.
// Grid 512 = (b:64) x (ic:8), each block sums 64 i's. Per k-iteration the
// block reads two full 2KB i-rows contiguously (lane -> 16B, io -> i parity).
// ---------------------------------------------------------------------------
__global__ __launch_bounds__(256) void k_sum0(const unsigned short* __restrict__ priors,
                                              float* __restrict__ out0) {
    const int b    = blockIdx.x >> 3;
    const int ic   = blockIdx.x & 7;
    const int t    = threadIdx.x;
    const int slot = t & 127;   // (o, v-half)
    const int io   = t >> 7;    // i parity
    const int o    = slot >> 1;
    const int vh   = slot & 1;

    float acc[8];
    #pragma unroll
    for (int j = 0; j < 8; ++j) acc[j] = 0.0f;

    const unsigned short* base = priors + (size_t)b * 524288 + (size_t)o * 16 + vh * 8;
    for (int k = 0; k < 32; ++k) {
        const int i = ic * 64 + k * 2 + io;
        ushort8 u = *(const ushort8*)(base + (size_t)i * 1024);
        #pragma unroll
        for (int j = 0; j < 8; ++j) acc[j] += bf2f(u[j]);
    }

    __shared__ float red[8 * 128];
    if (io == 1) {
        #pragma unroll
        for (int j = 0; j < 8; ++j) red[j * 128 + slot] = acc[j];
    }
    __syncthreads();
    if (io == 0) {
        float* dst = out0 + (size_t)b * 1024 + o * 16 + vh * 8;
        #pragma unroll
        for (int j = 0; j < 8; ++j) atomicAdd(dst + j, acc[j] + red[j * 128 + slot]);
    }
}

// ---------------------------------------------------------------------------
// K_route: one fused routing iteration.
//   logits[b,o,i] = dot(priors[b,i,o,:], normalize(out_prev[b,o,:]))
//   probs = softmax over o; out_next[b,o,v] += sum_i probs * priors
// Grid 512 = (b:64) x (h:8), each block owns i in [h*64, h*64+64).
// lane == o (wave of 64 == O), softmax is a wave shuffle-reduce.
// ---------------------------------------------------------------------------
__global__ __launch_bounds__(256) void k_route(const unsigned short* __restrict__ priors,
                                               const float* __restrict__ out_prev,
                                               float* __restrict__ out_next) {
    const int b    = blockIdx.x >> 3;
    const int h    = blockIdx.x & 7;
    const int t    = threadIdx.x;
    const int w    = t >> 6;
    const int lane = t & 63;

    __shared__ float noutT[16 * 64];   // [v][o]
    __shared__ float accbuf[4 * 1088]; // [wave][o*17+v] (pad 17: conflict-free)

    if (t < 64) {
        const float* po = out_prev + (size_t)b * 1024 + t * 16;
        float vv[16]; float n2 = 0.0f;
        #pragma unroll
        for (int j = 0; j < 16; ++j) { vv[j] = po[j]; n2 += vv[j] * vv[j]; }
        float n = fmaxf(sqrtf(n2), 1e-12f);
        float inv = 1.0f / n;
        #pragma unroll
        for (int j = 0; j < 16; ++j) noutT[j * 64 + t] = vv[j] * inv;
    }
    __syncthreads();

    float nr[16];
    #pragma unroll
    for (int j = 0; j < 16; ++j) nr[j] = noutT[j * 64 + lane];

    float acc[16];
    #pragma unroll
    for (int j = 0; j < 16; ++j) acc[j] = 0.0f;

    const size_t base = (size_t)b * 524288 + (size_t)lane * 16;
    for (int k = 0; k < 16; ++k) {
        const int i = h * 64 + w + 4 * k;
        const ushort8* pp = (const ushort8*)(priors + base + (size_t)i * 1024);
        ushort8 u0 = pp[0], u1 = pp[1];
        float pf[16];
        #pragma unroll
        for (int j = 0; j < 8; ++j) { pf[j] = bf2f(u0[j]); pf[8 + j] = bf2f(u1[j]); }

        float logit = 0.0f;
        #pragma unroll
        for (int j = 0; j < 16; ++j) logit = fmaf(pf[j], nr[j], logit);

        float m = logit;
        #pragma unroll
        for (int d = 1; d < 64; d <<= 1) m = fmaxf(m, __shfl_xor(m, d));
        float e = __expf(logit - m);
        float s = e;
        #pragma unroll
        for (int d = 1; d < 64; d <<= 1) s += __shfl_xor(s, d);
        float p = e / s;

        #pragma unroll
        for (int j = 0; j < 16; ++j) acc[j] = fmaf(p, pf[j], acc[j]);
    }

    #pragma unroll
    for (int j = 0; j < 16; ++j) accbuf[w * 1088 + lane * 17 + j] = acc[j];
    __syncthreads();

    for (int j = t; j < 1024; j += 256) {
        const int o = j >> 4, v = j & 15;
        const int idx = o * 17 + v;
        float s = accbuf[idx] + accbuf[1088 + idx] + accbuf[2176 + idx] + accbuf[3264 + idx];
        atomicAdd(out_next + (size_t)b * 1024 + j, s);
    }
}

// ---------------------------------------------------------------------------
// K_fin: out = squash(out3) + bias;  squash(x) = x * (||x|| / (1 + ||x||^2))
// ---------------------------------------------------------------------------
__global__ __launch_bounds__(64) void k_fin(const float* __restrict__ outl,
                                            const float* __restrict__ bias,
                                            float* __restrict__ out) {
    const int b = blockIdx.x;
    const int o = threadIdx.x;
    const float* p = outl + (size_t)b * 1024 + o * 16;
    float vv[16]; float n2 = 0.0f;
    #pragma unroll
    for (int j = 0; j < 16; ++j) { vv[j] = p[j]; n2 += vv[j] * vv[j]; }
    float n = sqrtf(n2);
    float scale = n / (1.0f + n2);
    float* q = out + (size_t)b * 1024 + o * 16;
    #pragma unroll
    for (int j = 0; j < 16; ++j) q[j] = vv[j] * scale + bias[o * 16 + j];
}

extern "C" void kernel_launch(void* const* d_in, const int* in_sizes, int n_in,
                              void* d_out, int out_size, void* d_ws, size_t ws_size,
                              hipStream_t stream) {
    const float* x    = (const float*)d_in[0];   // [64,512,8]
    const float* W    = (const float*)d_in[1];   // [64,512,16,8]
    const float* bias = (const float*)d_in[2];   // [64,16]
    float* out = (float*)d_out;                  // [64,64,16]

    unsigned short* priors = (unsigned short*)d_ws;                      // 67,108,864 B
    float* outb = (float*)((char*)d_ws + (size_t)64 * 512 * 64 * 16 * 2); // 4 x 65536 f32

    k_priors<<<512, 256, 0, stream>>>(W, x, priors, outb);
    k_sum0  <<<512, 256, 0, stream>>>(priors, outb);
    k_route <<<512, 256, 0, stream>>>(priors, outb,               outb + 65536);
    k_route <<<512, 256, 0, stream>>>(priors, outb + 65536,       outb + 2 * 65536);
    k_route <<<512, 256, 0, stream>>>(priors, outb + 2 * 65536,   outb + 3 * 65536);
    k_fin   <<<64, 64, 0, stream>>>(outb + 3 * 65536, bias, out);
}